// Round 5
// baseline (1327.997 us; speedup 1.0000x reference)
//
#include <hip/hip_runtime.h>

// QRNN: y = inp @ W^T + b -> z=tanh(y0), f=sig(y1), o=sig(y2)
//       h_t = f*z + (1-f)*h;  out0 = sig(o)*h [B,S,H];  out1 = h_{S-1} [B,H]
// Established (NaN-chain r1/r2 vs r3): inputs fp32, output fp32.
// r4->r5 fix: epilogue already stores ACTIVATED gates (o = sig(y_o)); K3 was
// applying sigmoid a second time -> exactly the observed 0.4629 absmax.
// K1: MFMA GEMM, fp32 global -> bf16-convert in regs -> swizzled LDS ->
//     16x16x32_bf16 MFMA, fused bias+activation epilogue -> gates in ws.
// K2: per-chunk linear-recurrence aggregates (G, A)  [h' = g*h + a]
// K3: prefix-fold aggregates + replay chunk + output gate (fp32 stores)

typedef unsigned short ushort_t;
typedef __bf16 bf16x8 __attribute__((ext_vector_type(8)));
typedef float f32x4 __attribute__((ext_vector_type(4)));

__device__ __forceinline__ ushort_t f2bf(float f) {
  unsigned int x = __builtin_bit_cast(unsigned int, f);
  x += 0x7fffu + ((x >> 16) & 1u);  // RNE
  return (ushort_t)(x >> 16);
}
__device__ __forceinline__ float bf2f(ushort_t u) {
  unsigned int x = ((unsigned int)u) << 16;
  return __builtin_bit_cast(float, x);
}
__device__ __forceinline__ float loadg(const float* p) { return *p; }
__device__ __forceinline__ float loadg(const ushort_t* p) { return bf2f(*p); }
__device__ __forceinline__ void storeg(float* p, float v) { *p = v; }
__device__ __forceinline__ void storeg(ushort_t* p, float v) { *p = f2bf(v); }

__device__ __forceinline__ float sig_f(float x) { return 1.0f / (1.0f + __expf(-x)); }
__device__ __forceinline__ float tanh_f(float x) { return 1.0f - 2.0f / (1.0f + __expf(2.0f * x)); }

// ---------------- K1: GEMM + activation epilogue ----------------
// A [M,K] fp32, Wt [N,K] fp32 (B^T layout), out [M,N] ACTIVATED gates.
// 128x128 tile, BK=64, 4 waves 2x2, each wave 4x4 MFMA 16x16x32 tiles.
// LDS: row r x 64 bf16; 16B k-group lg of row r stored at slot lg ^ (r&7)
// so ds_read_b128 fragment reads alias <=2-way (free, m136).
template <typename GT>
__global__ void __launch_bounds__(256) gemm_gates(
    const float* __restrict__ A, const float* __restrict__ Wt,
    const float* __restrict__ bias, GT* __restrict__ out,
    int M, int N, int K) {
  constexpr int BK = 64;
  __shared__ __align__(16) ushort_t As[128 * BK];
  __shared__ __align__(16) ushort_t Bs[128 * BK];
  const int tid = threadIdx.x;
  const int lane = tid & 63;
  const int wv = tid >> 6;  // 0..3
  const int nblk = N >> 7;
  const int bn = blockIdx.x % nblk;
  const int bm = blockIdx.x / nblk;
  const int m0 = bm << 7, n0 = bn << 7;
  const int wm = (wv >> 1) << 6, wn = (wv & 1) << 6;

  f32x4 acc[4][4] = {};

  // Staging: 256 threads x 8 iters x float4 (=4 bf16 after convert, 8B).
  // iter q: row = q*16 + (tid>>4); row&7 == (tid>>4)&7 -> dest q-invariant.
  const int srow = tid >> 4;             // 0..15
  const int sk4 = tid & 15;              // float4 index within row
  const int g = sk4 >> 1, half = sk4 & 1;
  const int k4p = ((g ^ (srow & 7)) << 1) | half;  // swizzled 8B slot
  const int ldst = srow * 64 + k4p * 4;  // ushort offset for q=0

  for (int kt = 0; kt < K; kt += BK) {
    __syncthreads();
#pragma unroll
    for (int q = 0; q < 8; ++q) {
      const int row = q * 16 + srow;
      const float4 va = *(const float4*)&A[(size_t)(m0 + row) * K + kt + sk4 * 4];
      const float4 vb = *(const float4*)&Wt[(size_t)(n0 + row) * K + kt + sk4 * 4];
      ushort4 wa, wb;
      wa.x = f2bf(va.x); wa.y = f2bf(va.y); wa.z = f2bf(va.z); wa.w = f2bf(va.w);
      wb.x = f2bf(vb.x); wb.y = f2bf(vb.y); wb.z = f2bf(vb.z); wb.w = f2bf(vb.w);
      *(ushort4*)&As[q * 16 * 64 + ldst] = wa;
      *(ushort4*)&Bs[q * 16 * 64 + ldst] = wb;
    }
    __syncthreads();
#pragma unroll
    for (int ks = 0; ks < 2; ++ks) {
      bf16x8 af[4], bfr[4];
#pragma unroll
      for (int t = 0; t < 4; ++t) {
        const int ar = wm + t * 16 + (lane & 15);
        const int ag = ((ks << 2) + (lane >> 4)) ^ (ar & 7);
        af[t] = *(const bf16x8*)&As[ar * 64 + ag * 8];
        const int br = wn + t * 16 + (lane & 15);
        const int bg = ((ks << 2) + (lane >> 4)) ^ (br & 7);
        bfr[t] = *(const bf16x8*)&Bs[br * 64 + bg * 8];
      }
#pragma unroll
      for (int i = 0; i < 4; ++i)
#pragma unroll
        for (int j = 0; j < 4; ++j)
          acc[i][j] =
              __builtin_amdgcn_mfma_f32_16x16x32_bf16(af[i], bfr[j], acc[i][j], 0, 0, 0);
    }
  }

  // Epilogue. C/D layout (m89/m91): col = lane&15, row = (lane>>4)*4 + reg.
  const int gcat = n0 >> 10;  // 0:z(tanh) 1:f(sig) 2:o(sig); uniform per block
  const int cn = lane & 15;
  const int cm = (lane >> 4) << 2;
#pragma unroll
  for (int j = 0; j < 4; ++j) {
    const int n = n0 + wn + j * 16 + cn;
    const float bv = bias[n];
#pragma unroll
    for (int i = 0; i < 4; ++i) {
#pragma unroll
      for (int r = 0; r < 4; ++r) {
        const int m = m0 + wm + i * 16 + cm + r;
        const float y = acc[i][j][r] + bv;
        const float v = (gcat == 0) ? tanh_f(y) : sig_f(y);
        storeg(&out[(size_t)m * N + n], v);
      }
    }
  }
}

// ---------------- K2: chunk aggregates ----------------
// h_t = f*z + (1-f)*h == g*h + a, g=1-f, a=f*z. Chunk: h_end = Aa + G*h_in.
// gates hold ACTIVATED z,f.
template <typename GT>
__global__ void __launch_bounds__(256) qrnn_chunk_agg(
    const GT* __restrict__ gates, float* __restrict__ aggG,
    float* __restrict__ aggA, int b0, int S, int H, int C, int L) {
  const int nhb = H >> 8;
  const int hb = blockIdx.x % nhb;
  const int c = (blockIdx.x / nhb) % C;
  const int bl = blockIdx.x / (nhb * C);  // local batch within group
  const int h = (hb << 8) + threadIdx.x;
  const int N3 = 3 * H;
  const GT* pz = gates + ((size_t)(bl * S + c * L)) * N3 + h;
  const GT* pf = pz + H;
  float G = 1.0f, Aa = 0.0f;
#pragma unroll 4
  for (int j = 0; j < L; ++j) {
    const float z = loadg(pz);
    const float f = loadg(pf);
    const float g = 1.0f - f;
    Aa = fmaf(g, Aa, f * z);
    G *= g;
    pz += N3;
    pf += N3;
  }
  const size_t idx = ((size_t)((b0 + bl) * C + c)) * H + h;
  aggG[idx] = G;
  aggA[idx] = Aa;
}

// ---------------- K3: prefix fold + replay + output gate ----------------
// gates hold ACTIVATED z,f,o -> o is used DIRECTLY (no second sigmoid!).
template <typename GT>
__global__ void __launch_bounds__(256) qrnn_scan_apply(
    const GT* __restrict__ gates, const float* __restrict__ aggG,
    const float* __restrict__ aggA, float* __restrict__ out,
    int b0, int B, int S, int H, int C, int L) {
  const int nhb = H >> 8;
  const int hb = blockIdx.x % nhb;
  const int c = (blockIdx.x / nhb) % C;
  const int bl = blockIdx.x / (nhb * C);
  const int bg = b0 + bl;  // global batch
  const int h = (hb << 8) + threadIdx.x;
  const int N3 = 3 * H;

  float hc = 0.0f;  // h at chunk start (c block-uniform -> no divergence)
  for (int cc = 0; cc < c; ++cc) {
    const size_t idx = ((size_t)(bg * C + cc)) * H + h;
    hc = fmaf(aggG[idx], hc, aggA[idx]);
  }

  const GT* pz = gates + ((size_t)(bl * S + c * L)) * N3 + h;
  const GT* pf = pz + H;
  const GT* po = pf + H;
  size_t oidx = ((size_t)(bg * S + c * L)) * H + h;
#pragma unroll 4
  for (int j = 0; j < L; ++j) {
    const float z = loadg(pz);
    const float f = loadg(pf);
    const float o = loadg(po);  // already sigmoid(y_o)
    hc = fmaf(1.0f - f, hc, f * z);
    out[oidx] = o * hc;  // FIX: was sig_f(o)*hc (double sigmoid)
    pz += N3; pf += N3; po += N3; oidx += H;
  }
  if (c == C - 1) {  // final state c[:, -1] -> second output [B,H]
    out[(size_t)B * S * H + (size_t)bg * H + h] = hc;
  }
}

template <typename GT>
static void run_groups(const float* inp, const float* W, const float* b,
                       float* out, void* gates_ws, float* aggG, float* aggA,
                       int Bg, int B, int S, int H, int K, int C, int L,
                       hipStream_t stream) {
  const int N = 3 * H;
  GT* gates = (GT*)gates_ws;
  for (int b0 = 0; b0 < B; b0 += Bg) {
    const int Mg = Bg * S;
    const int gemm_grid = (Mg / 128) * (N / 128);
    const int scan_grid = Bg * C * (H / 256);
    gemm_gates<GT><<<gemm_grid, 256, 0, stream>>>(
        inp + (size_t)b0 * S * K, W, b, gates, Mg, N, K);
    qrnn_chunk_agg<GT><<<scan_grid, 256, 0, stream>>>(
        gates, aggG, aggA, b0, S, H, C, L);
    qrnn_scan_apply<GT><<<scan_grid, 256, 0, stream>>>(
        gates, aggG, aggA, out, b0, B, S, H, C, L);
  }
}

extern "C" void kernel_launch(void* const* d_in, const int* in_sizes, int n_in,
                              void* d_out, int out_size, void* d_ws, size_t ws_size,
                              hipStream_t stream) {
  (void)in_sizes; (void)n_in; (void)out_size;
  const float* inp = (const float*)d_in[0];  // [B,S,D] fp32
  const float* W = (const float*)d_in[1];    // [3H,D] fp32
  const float* b = (const float*)d_in[2];    // [3H] fp32
  float* out = (float*)d_out;                // [B,S,H] ++ [B,H] fp32

  constexpr int B = 16, S = 2048, H = 1024, K = 1024;
  constexpr int C = 16, L = S / C;

  // ws layout: [aggG fp32 B*C*H][aggA fp32 B*C*H][gates (group-local)]
  const size_t agg_elems = (size_t)B * C * H;
  float* aggG = (float*)d_ws;
  float* aggA = aggG + agg_elems;
  void* gates_ws = (void*)((char*)d_ws + 2 * agg_elems * sizeof(float));
  const size_t hdr = 2 * agg_elems * sizeof(float);
  const size_t gates_avail = (ws_size > hdr) ? ws_size - hdr : 0;

  // Largest batch-group whose gates fit; prefer fp32 gates (exact scan).
  int Bg_f32 = 0, Bg_bf16 = 0;
  for (int g = 16; g >= 1; g >>= 1)
    if ((size_t)g * S * 3 * H * sizeof(float) <= gates_avail) { Bg_f32 = g; break; }
  if (!Bg_f32)
    for (int g = 16; g >= 1; g >>= 1)
      if ((size_t)g * S * 3 * H * sizeof(ushort_t) <= gates_avail) { Bg_bf16 = g; break; }

  if (Bg_f32) {
    run_groups<float>(inp, W, b, out, gates_ws, aggG, aggA, Bg_f32,
                      B, S, H, K, C, L, stream);
  } else if (Bg_bf16) {
    run_groups<ushort_t>(inp, W, b, out, gates_ws, aggG, aggA, Bg_bf16,
                         B, S, H, K, C, L, stream);
  }
}